// Round 6
// baseline (624.079 us; speedup 1.0000x reference)
//
#include <hip/hip_runtime.h>
#include <math.h>

#define N_PTS 8192
#define B_SZ 4
#define SEED_NUM 409
#define FPS_THREADS 512
#define LTOT 653  // 65+98+131+163+196

// Exact IEEE f32 squared distance, same op order as the reference:
// ((dx*dx + dy*dy) + dz*dz), no FMA contraction.
__device__ __forceinline__ float sqdist(float ax, float ay, float az,
                                        float bx, float by, float bz) {
  float dx = __fsub_rn(ax, bx);
  float dy = __fsub_rn(ay, by);
  float dz = __fsub_rn(az, bz);
  return __fadd_rn(__fadd_rn(__fmul_rn(dx, dx), __fmul_rn(dy, dy)),
                   __fmul_rn(dz, dz));
}

#define FOR16(M) \
  M(0) M(1) M(2) M(3) M(4) M(5) M(6) M(7) \
  M(8) M(9) M(10) M(11) M(12) M(13) M(14) M(15)

// ---------------------------------------------------------------------------
// Kernel 1: farthest point sampling. One block per batch (4 blocks).
// R5 change: seeds are buffered in LDS during the 409-step loop and bulk-
// copied to global at the end. Previously tid0 issued a global seed store
// every step; __syncthreads() forces s_waitcnt vmcnt(0) before s_barrier in
// that wave, so ALL waves waited ~300-900 cyc/step on the store drain.
// LDS writes retire in ~40 cyc and overlap the distance math.
// ---------------------------------------------------------------------------
__global__ __launch_bounds__(FPS_THREADS, 1) void fps_kernel(
    const float* __restrict__ pcs, float* __restrict__ seeds) {
  const int b = blockIdx.x;
  const int tid = threadIdx.x;
  const int lane = tid & 63, wid = tid >> 6;  // 8 waves
  const float* base = pcs + (size_t)b * N_PTS * 3;

  __shared__ float spts[N_PTS * 3];        // 96 KiB: winner-coord broadcast
  __shared__ float seedbuf[SEED_NUM * 3];  // 4.8 KiB: deferred seed output
  __shared__ unsigned long long red[2][8];

#define FPS_DECL(k) float px##k, py##k, pz##k, md##k;
  FOR16(FPS_DECL)
#undef FPS_DECL

#define FPS_INIT(k)                              \
  {                                              \
    const int i = tid + (k)*FPS_THREADS;         \
    px##k = base[i * 3 + 0];                     \
    py##k = base[i * 3 + 1];                     \
    pz##k = base[i * 3 + 2];                     \
    md##k = 1e10f; /* ref 1e10 -> f32 exact */   \
    spts[i * 3 + 0] = px##k;                     \
    spts[i * 3 + 1] = py##k;                     \
    spts[i * 3 + 2] = pz##k;                     \
  }
  FOR16(FPS_INIT)
#undef FPS_INIT

  // Pin coords in VGPRs (asm results can't be rematerialized from memory).
#define FPS_PIN(k) asm volatile("" : "+v"(px##k), "+v"(py##k), "+v"(pz##k));
  FOR16(FPS_PIN)
#undef FPS_PIN

  float cx = base[0], cy = base[1], cz = base[2];

  for (int s = 0; s < SEED_NUM; ++s) {
    if (tid == 0) {  // LDS, not global: no vmcnt drain at the barrier
      seedbuf[s * 3 + 0] = cx;
      seedbuf[s * 3 + 1] = cy;
      seedbuf[s * 3 + 2] = cz;
    }
    float bv = -1.0f;
    int bi = 0;
    // i = tid + k*512: index increases with k, so strict '>' keeps the
    // first (smallest) index on ties within a thread.
#define FPS_UPD(k)                                                  \
  {                                                                 \
    const float d2 = sqdist(px##k, py##k, pz##k, cx, cy, cz);       \
    const float m = fminf(md##k, d2);                               \
    md##k = m;                                                      \
    if (m > bv) { bv = m; bi = tid + (k)*FPS_THREADS; }             \
  }
    FOR16(FPS_UPD)
#undef FPS_UPD
    unsigned long long key =
        ((unsigned long long)__float_as_uint(bv) << 32) |
        (unsigned long long)(unsigned)(N_PTS - 1 - bi);
#pragma unroll
    for (int off = 32; off > 0; off >>= 1) {
      const unsigned long long o = __shfl_down(key, off);
      key = (o > key) ? o : key;
    }
    if (lane == 0) red[s & 1][wid] = key;
    __syncthreads();
    unsigned long long kmax = red[s & 1][0];
#pragma unroll
    for (int w = 1; w < 8; ++w) {
      const unsigned long long o = red[s & 1][w];
      kmax = (o > kmax) ? o : kmax;
    }
    const int ci = N_PTS - 1 - (int)(unsigned)(kmax & 0xffffffffull);
    cx = spts[ci * 3 + 0];
    cy = spts[ci * 3 + 1];
    cz = spts[ci * 3 + 2];
  }

  // bulk seed writeback (last seedbuf write was ordered by the final
  // in-loop barrier; one more for clarity/safety is cheap -- once)
  __syncthreads();
  float* sg = seeds + (size_t)b * SEED_NUM * 3;
  for (int i = tid; i < SEED_NUM * 3; i += FPS_THREADS) sg[i] = seedbuf[i];
}

// ---------------------------------------------------------------------------
// Kernel 2: one block per group, ALL 5 percentages at once (unchanged from
// round 5 — ~10-30 us). Order-free atomic-append collection (valid-sets nest,
// KNN result is set-order-independent); ordered-recompaction fallback for the
// measure-zero cnt>K case; 4-thread/row two-min KNN with shfl_xor merge.
// ---------------------------------------------------------------------------
__global__ __launch_bounds__(256) void group_kernel(
    const float* __restrict__ pcs, const float* __restrict__ seeds,
    double* __restrict__ totS /*[5]*/, double* __restrict__ accA /*[5][4]*/) {
  const int g = blockIdx.x;  // 0 .. B*SEED_NUM-1
  const int b = g / SEED_NUM;
  const int tid = threadIdx.x;
  const int lane = tid & 63, wid = tid >> 6;

  const int Kc[5] = {65, 98, 131, 163, 196};
  const int off[5] = {0, 65, 163, 294, 457};
  const double Pd[5] = {0.004, 0.006, 0.008, 0.01, 0.012};
  float r2c[5], expnf[5], expdc[5];
#pragma unroll
  for (int p = 0; p < 5; ++p) {
    const double pd = Pd[p];
    const double rd = sqrt(pd);
    r2c[p] = (float)(rd * rd);                     // weak f32 cast of r*r
    const double expn_d = 8192.0 * pd;
    expnf[p] = (float)expn_d;
    expdc[p] = sqrtf((float)(M_PI / expn_d * pd));  // expect_dis (= sqrt(pi/N))
  }

  const float* base = pcs + (size_t)b * N_PTS * 3;
  const float* sp = seeds + (size_t)g * 3;
  const float sx = sp[0], sy = sp[1], sz = sp[2];

  __shared__ float lx[LTOT], ly[LTOT], lz[LTOT];
  __shared__ int cnt[5];
  __shared__ int wtot[4];     // fallback path only
  __shared__ double wsum[4];

  if (tid < 5) cnt[tid] = 0;
  __syncthreads();

  // ---- single barrier-free scan: d2 once, append to each nested list ----
  const float r2max = r2c[4];
  for (int i = tid; i < N_PTS; i += 256) {
    const float x = base[i * 3 + 0];
    const float y = base[i * 3 + 1];
    const float z = base[i * 3 + 2];
    const float d2 = sqdist(x, y, z, sx, sy, sz);
    if (d2 < r2max) {
#pragma unroll
      for (int p = 0; p < 5; ++p) {
        if (d2 < r2c[p]) {
          const int pos = atomicAdd(&cnt[p], 1);
          if (pos < Kc[p]) {
            lx[off[p] + pos] = x;
            ly[off[p] + pos] = y;
            lz[off[p] + pos] = z;
          }
        }
      }
    }
  }
  __syncthreads();

  // ---- rare fallback: cnt>K needs the K smallest indices (ordered) ----
#pragma unroll
  for (int p = 0; p < 5; ++p) {
    if (cnt[p] > Kc[p]) {  // block-uniform (LDS value, post-barrier)
      int run = 0;
      for (int base_i = 0; base_i < N_PTS; base_i += 256) {
        const int i = base_i + tid;
        const float x = base[i * 3 + 0];
        const float y = base[i * 3 + 1];
        const float z = base[i * 3 + 2];
        const float d2 = sqdist(x, y, z, sx, sy, sz);
        const bool valid = d2 < r2c[p];
        const unsigned long long m = __ballot(valid);
        if (lane == 0) wtot[wid] = __popcll(m);
        __syncthreads();
        int pos = run + __popcll(m & ((1ull << lane) - 1ull));
        for (int w = 0; w < wid; ++w) pos += wtot[w];
        if (valid && pos < Kc[p]) {
          lx[off[p] + pos] = x; ly[off[p] + pos] = y; lz[off[p] + pos] = z;
        }
        run += wtot[0] + wtot[1] + wtot[2] + wtot[3];
        __syncthreads();
      }
    }
  }

  // ---- KNN + clutter per percentage: 4 threads/row, shfl two-min merge ----
#pragma unroll
  for (int p = 0; p < 5; ++p) {
    const int gn = min(cnt[p], Kc[p]);  // gnum >= 1 (seed itself is in pcs)
    const float ed = expdc[p];
    const int lb = off[p];
    double localS = 0.0;
    for (int r0 = 0; r0 < gn; r0 += 64) {
      const int row = r0 + (tid >> 2);
      const int sub = tid & 3;
      float m1 = INFINITY, m2 = INFINITY;
      if (row < gn) {
        const float xi = lx[lb + row], yi = ly[lb + row], zi = lz[lb + row];
        for (int j = sub; j < gn; j += 4) {
          const float d2 = sqdist(xi, yi, zi, lx[lb + j], ly[lb + j], lz[lb + j]);
          if (d2 < m1) { m2 = m1; m1 = d2; }
          else if (d2 < m2) { m2 = d2; }
        }
      }
      // merge (m1,m2) pairs across the 4 sub-lanes (multiset two-min)
#pragma unroll
      for (int d = 1; d <= 2; d <<= 1) {
        const float om1 = __shfl_xor(m1, d);
        const float om2 = __shfl_xor(m2, d);
        const float lo = fminf(m1, om1);
        const float hi = fmaxf(m1, om1);
        m2 = fminf(fminf(m2, om2), hi);
        m1 = lo;
      }
      if (row < gn && sub == 0) {
        const float nn2 = (m2 > 1e37f) ? 0.0f : m2;  // inf (gn==1) -> 0
        const float nnd = (nn2 > 0.0f) ? sqrtf(nn2) : 0.0f;
        const float diff = __fsub_rn(nnd, ed);
        const float clut = __fdiv_rn(__fmul_rn(diff, diff),
                                     __fadd_rn(ed, 1e-12f));
        localS += (double)clut;
      }
    }
#pragma unroll
    for (int o = 32; o > 0; o >>= 1) localS += __shfl_down(localS, o);
    if (lane == 0) wsum[wid] = localS;
    __syncthreads();
    if (tid == 0) {
      const double S = wsum[0] + wsum[1] + wsum[2] + wsum[3];
      atomicAdd(&totS[p], S);
      const float gf = (float)gn;
      const float dd = __fsub_rn(gf, expnf[p]);
      const float imb = __fdiv_rn(__fmul_rn(dd, dd), expnf[p]);
      atomicAdd(&accA[p * 4 + b], (double)imb / (double)gf);
    }
    __syncthreads();  // wsum reused next p
  }
}

// ---------------------------------------------------------------------------
// Kernel 3: loss[b] = (1/5) * sum_p totS[p] * (accA[p][b] / 409)
// ---------------------------------------------------------------------------
__global__ void finalize_kernel(const double* __restrict__ totS,
                                const double* __restrict__ accA,
                                float* __restrict__ out) {
  const int b = threadIdx.x;
  if (b < B_SZ) {
    double acc = 0.0;
    for (int p = 0; p < 5; ++p)
      acc += totS[p] * (accA[p * 4 + b] / (double)SEED_NUM);
    out[b] = (float)(acc / 5.0);
  }
}

__global__ void zero_kernel(double* __restrict__ ptr) {
  const int t = threadIdx.x;
  if (t < 25) ptr[t] = 0.0;  // totS[5] + accA[20]
}

extern "C" void kernel_launch(void* const* d_in, const int* in_sizes, int n_in,
                              void* d_out, int out_size, void* d_ws,
                              size_t ws_size, hipStream_t stream) {
  (void)in_sizes; (void)n_in; (void)out_size; (void)ws_size;
  const float* pcs = (const float*)d_in[0];
  float* out = (float*)d_out;

  // ws layout: seeds (B*409*3 f32 = 19632 B, 8-aligned), then 25 doubles.
  float* seeds = (float*)d_ws;
  double* sums = (double*)((char*)d_ws + 19632);

  zero_kernel<<<1, 32, 0, stream>>>(sums);
  fps_kernel<<<B_SZ, FPS_THREADS, 0, stream>>>(pcs, seeds);
  group_kernel<<<B_SZ * SEED_NUM, 256, 0, stream>>>(pcs, seeds, sums, sums + 5);
  finalize_kernel<<<1, 64, 0, stream>>>(sums, sums + 5, out);
}

// Round 8
// 572.124 us; speedup vs baseline: 1.0908x; 1.0908x over previous
//
#include <hip/hip_runtime.h>
#include <math.h>

#define N_PTS 8192
#define B_SZ 4
#define SEED_NUM 409
#define FPS_THREADS 512
#define LTOT 653  // 65+98+131+163+196

// Exact IEEE f32 squared distance, same op order as the reference:
// ((dx*dx + dy*dy) + dz*dz), no FMA contraction.
__device__ __forceinline__ float sqdist(float ax, float ay, float az,
                                        float bx, float by, float bz) {
  float dx = __fsub_rn(ax, bx);
  float dy = __fsub_rn(ay, by);
  float dz = __fsub_rn(az, bz);
  return __fadd_rn(__fadd_rn(__fmul_rn(dx, dx), __fmul_rn(dy, dy)),
                   __fmul_rn(dz, dz));
}

#define FOR16(M) \
  M(0) M(1) M(2) M(3) M(4) M(5) M(6) M(7) \
  M(8) M(9) M(10) M(11) M(12) M(13) M(14) M(15)

// u64 lane-move via two 32-bit DPP ops. DPP control fields must be
// call-site integer constant expressions -> template parameters.
// shr-stages: bound_ctrl=1 (OOB lanes read 0 — harmless for max of
// non-negative keys). bcast stages: keep `old` in masked-off rows so the
// subsequent max is a no-op there.
template <int CTRL>
__device__ __forceinline__ unsigned long long dpp_u64_bc1(
    unsigned long long k) {
  const unsigned lo2 = (unsigned)__builtin_amdgcn_update_dpp(
      0, (int)(unsigned)k, CTRL, 0xf, 0xf, true);
  const unsigned hi2 = (unsigned)__builtin_amdgcn_update_dpp(
      0, (int)(unsigned)(k >> 32), CTRL, 0xf, 0xf, true);
  return ((unsigned long long)hi2 << 32) | lo2;
}
template <int CTRL, int ROW_MASK>
__device__ __forceinline__ unsigned long long dpp_u64_keep(
    unsigned long long k) {
  const unsigned lo2 = (unsigned)__builtin_amdgcn_update_dpp(
      (int)(unsigned)k, (int)(unsigned)k, CTRL, ROW_MASK, 0xf, false);
  const unsigned hi2 = (unsigned)__builtin_amdgcn_update_dpp(
      (int)(unsigned)(k >> 32), (int)(unsigned)(k >> 32), CTRL, ROW_MASK, 0xf,
      false);
  return ((unsigned long long)hi2 << 32) | lo2;
}

// ---------------------------------------------------------------------------
// Kernel 1: farthest point sampling. One block per batch (4 blocks).
// R6/R7 change: wave argmax-reduce via DPP (row_shr 1/2/4/8 + ROW_BCAST15/31),
// replacing __shfl_down which compiles to ds_bpermute (~120cyc LDS-latency
// each; the 6-stage dependent chain was ~720 cyc of the 2725-cyc step).
// DPP is pure VALU (~4-8 cyc/stage). Max lands in lane 63 of each wave.
// (R5 note: per-step global seed store was NOT on the critical path —
// LDS seedbuf kept anyway. R4 note: asm "+v" pin keeps coords in VGPRs.)
// ---------------------------------------------------------------------------
__global__ __launch_bounds__(FPS_THREADS, 1) void fps_kernel(
    const float* __restrict__ pcs, float* __restrict__ seeds) {
  const int b = blockIdx.x;
  const int tid = threadIdx.x;
  const int lane = tid & 63, wid = tid >> 6;  // 8 waves
  const float* base = pcs + (size_t)b * N_PTS * 3;

  __shared__ float spts[N_PTS * 3];        // 96 KiB: winner-coord broadcast
  __shared__ float seedbuf[SEED_NUM * 3];  // 4.8 KiB: deferred seed output
  __shared__ unsigned long long red[2][8];

#define FPS_DECL(k) float px##k, py##k, pz##k, md##k;
  FOR16(FPS_DECL)
#undef FPS_DECL

#define FPS_INIT(k)                              \
  {                                              \
    const int i = tid + (k)*FPS_THREADS;         \
    px##k = base[i * 3 + 0];                     \
    py##k = base[i * 3 + 1];                     \
    pz##k = base[i * 3 + 2];                     \
    md##k = 1e10f; /* ref 1e10 -> f32 exact */   \
    spts[i * 3 + 0] = px##k;                     \
    spts[i * 3 + 1] = py##k;                     \
    spts[i * 3 + 2] = pz##k;                     \
  }
  FOR16(FPS_INIT)
#undef FPS_INIT

  // Pin coords in VGPRs (asm results can't be rematerialized from memory).
#define FPS_PIN(k) asm volatile("" : "+v"(px##k), "+v"(py##k), "+v"(pz##k));
  FOR16(FPS_PIN)
#undef FPS_PIN

  float cx = base[0], cy = base[1], cz = base[2];

  for (int s = 0; s < SEED_NUM; ++s) {
    if (tid == 0) {
      seedbuf[s * 3 + 0] = cx;
      seedbuf[s * 3 + 1] = cy;
      seedbuf[s * 3 + 2] = cz;
    }
    float bv = -1.0f;
    int bi = 0;
    // i = tid + k*512: index increases with k, so strict '>' keeps the
    // first (smallest) index on ties within a thread.
#define FPS_UPD(k)                                                  \
  {                                                                 \
    const float d2 = sqdist(px##k, py##k, pz##k, cx, cy, cz);       \
    const float m = fminf(md##k, d2);                               \
    md##k = m;                                                      \
    if (m > bv) { bv = m; bi = tid + (k)*FPS_THREADS; }             \
  }
    FOR16(FPS_UPD)
#undef FPS_UPD
    // packed argmax key: bv >= 0 so f32 bits are monotone; u64 max ==
    // (max value, tie -> min index) == jnp.argmax semantics.
    unsigned long long key =
        ((unsigned long long)__float_as_uint(bv) << 32) |
        (unsigned long long)(unsigned)(N_PTS - 1 - bi);
    unsigned long long o;
    o = dpp_u64_bc1<0x111>(key);         key = (o > key) ? o : key;  // shr 1
    o = dpp_u64_bc1<0x112>(key);         key = (o > key) ? o : key;  // shr 2
    o = dpp_u64_bc1<0x114>(key);         key = (o > key) ? o : key;  // shr 4
    o = dpp_u64_bc1<0x118>(key);         key = (o > key) ? o : key;  // shr 8
    o = dpp_u64_keep<0x142, 0xa>(key);   key = (o > key) ? o : key;  // bcast15
    o = dpp_u64_keep<0x143, 0xc>(key);   key = (o > key) ? o : key;  // bcast31
    if (lane == 63) red[s & 1][wid] = key;
    __syncthreads();
    unsigned long long kmax = red[s & 1][0];
#pragma unroll
    for (int w = 1; w < 8; ++w) {
      const unsigned long long t = red[s & 1][w];
      kmax = (t > kmax) ? t : kmax;
    }
    const int ci = N_PTS - 1 - (int)(unsigned)(kmax & 0xffffffffull);
    cx = spts[ci * 3 + 0];
    cy = spts[ci * 3 + 1];
    cz = spts[ci * 3 + 2];
  }

  // bulk seed writeback (ordered by the final in-loop barrier)
  __syncthreads();
  float* sg = seeds + (size_t)b * SEED_NUM * 3;
  for (int i = tid; i < SEED_NUM * 3; i += FPS_THREADS) sg[i] = seedbuf[i];
}

// ---------------------------------------------------------------------------
// Kernel 2: one block per group, ALL 5 percentages at once (unchanged —
// ~10-30 us). Order-free atomic-append collection (valid-sets nest, KNN is
// set-order-independent); ordered-recompaction fallback for the measure-zero
// cnt>K case; 4-thread/row two-min KNN with shfl_xor merge.
// ---------------------------------------------------------------------------
__global__ __launch_bounds__(256) void group_kernel(
    const float* __restrict__ pcs, const float* __restrict__ seeds,
    double* __restrict__ totS /*[5]*/, double* __restrict__ accA /*[5][4]*/) {
  const int g = blockIdx.x;  // 0 .. B*SEED_NUM-1
  const int b = g / SEED_NUM;
  const int tid = threadIdx.x;
  const int lane = tid & 63, wid = tid >> 6;

  const int Kc[5] = {65, 98, 131, 163, 196};
  const int off[5] = {0, 65, 163, 294, 457};
  const double Pd[5] = {0.004, 0.006, 0.008, 0.01, 0.012};
  float r2c[5], expnf[5], expdc[5];
#pragma unroll
  for (int p = 0; p < 5; ++p) {
    const double pd = Pd[p];
    const double rd = sqrt(pd);
    r2c[p] = (float)(rd * rd);                     // weak f32 cast of r*r
    const double expn_d = 8192.0 * pd;
    expnf[p] = (float)expn_d;
    expdc[p] = sqrtf((float)(M_PI / expn_d * pd));  // expect_dis (= sqrt(pi/N))
  }

  const float* base = pcs + (size_t)b * N_PTS * 3;
  const float* sp = seeds + (size_t)g * 3;
  const float sx = sp[0], sy = sp[1], sz = sp[2];

  __shared__ float lx[LTOT], ly[LTOT], lz[LTOT];
  __shared__ int cnt[5];
  __shared__ int wtot[4];     // fallback path only
  __shared__ double wsum[4];

  if (tid < 5) cnt[tid] = 0;
  __syncthreads();

  // ---- single barrier-free scan: d2 once, append to each nested list ----
  const float r2max = r2c[4];
  for (int i = tid; i < N_PTS; i += 256) {
    const float x = base[i * 3 + 0];
    const float y = base[i * 3 + 1];
    const float z = base[i * 3 + 2];
    const float d2 = sqdist(x, y, z, sx, sy, sz);
    if (d2 < r2max) {
#pragma unroll
      for (int p = 0; p < 5; ++p) {
        if (d2 < r2c[p]) {
          const int pos = atomicAdd(&cnt[p], 1);
          if (pos < Kc[p]) {
            lx[off[p] + pos] = x;
            ly[off[p] + pos] = y;
            lz[off[p] + pos] = z;
          }
        }
      }
    }
  }
  __syncthreads();

  // ---- rare fallback: cnt>K needs the K smallest indices (ordered) ----
#pragma unroll
  for (int p = 0; p < 5; ++p) {
    if (cnt[p] > Kc[p]) {  // block-uniform (LDS value, post-barrier)
      int run = 0;
      for (int base_i = 0; base_i < N_PTS; base_i += 256) {
        const int i = base_i + tid;
        const float x = base[i * 3 + 0];
        const float y = base[i * 3 + 1];
        const float z = base[i * 3 + 2];
        const float d2 = sqdist(x, y, z, sx, sy, sz);
        const bool valid = d2 < r2c[p];
        const unsigned long long m = __ballot(valid);
        if (lane == 0) wtot[wid] = __popcll(m);
        __syncthreads();
        int pos = run + __popcll(m & ((1ull << lane) - 1ull));
        for (int w = 0; w < wid; ++w) pos += wtot[w];
        if (valid && pos < Kc[p]) {
          lx[off[p] + pos] = x; ly[off[p] + pos] = y; lz[off[p] + pos] = z;
        }
        run += wtot[0] + wtot[1] + wtot[2] + wtot[3];
        __syncthreads();
      }
    }
  }

  // ---- KNN + clutter per percentage: 4 threads/row, shfl two-min merge ----
#pragma unroll
  for (int p = 0; p < 5; ++p) {
    const int gn = min(cnt[p], Kc[p]);  // gnum >= 1 (seed itself is in pcs)
    const float ed = expdc[p];
    const int lb = off[p];
    double localS = 0.0;
    for (int r0 = 0; r0 < gn; r0 += 64) {
      const int row = r0 + (tid >> 2);
      const int sub = tid & 3;
      float m1 = INFINITY, m2 = INFINITY;
      if (row < gn) {
        const float xi = lx[lb + row], yi = ly[lb + row], zi = lz[lb + row];
        for (int j = sub; j < gn; j += 4) {
          const float d2 = sqdist(xi, yi, zi, lx[lb + j], ly[lb + j], lz[lb + j]);
          if (d2 < m1) { m2 = m1; m1 = d2; }
          else if (d2 < m2) { m2 = d2; }
        }
      }
      // merge (m1,m2) pairs across the 4 sub-lanes (multiset two-min)
#pragma unroll
      for (int d = 1; d <= 2; d <<= 1) {
        const float om1 = __shfl_xor(m1, d);
        const float om2 = __shfl_xor(m2, d);
        const float lo = fminf(m1, om1);
        const float hi = fmaxf(m1, om1);
        m2 = fminf(fminf(m2, om2), hi);
        m1 = lo;
      }
      if (row < gn && sub == 0) {
        const float nn2 = (m2 > 1e37f) ? 0.0f : m2;  // inf (gn==1) -> 0
        const float nnd = (nn2 > 0.0f) ? sqrtf(nn2) : 0.0f;
        const float diff = __fsub_rn(nnd, ed);
        const float clut = __fdiv_rn(__fmul_rn(diff, diff),
                                     __fadd_rn(ed, 1e-12f));
        localS += (double)clut;
      }
    }
#pragma unroll
    for (int o = 32; o > 0; o >>= 1) localS += __shfl_down(localS, o);
    if (lane == 0) wsum[wid] = localS;
    __syncthreads();
    if (tid == 0) {
      const double S = wsum[0] + wsum[1] + wsum[2] + wsum[3];
      atomicAdd(&totS[p], S);
      const float gf = (float)gn;
      const float dd = __fsub_rn(gf, expnf[p]);
      const float imb = __fdiv_rn(__fmul_rn(dd, dd), expnf[p]);
      atomicAdd(&accA[p * 4 + b], (double)imb / (double)gf);
    }
    __syncthreads();  // wsum reused next p
  }
}

// ---------------------------------------------------------------------------
// Kernel 3: loss[b] = (1/5) * sum_p totS[p] * (accA[p][b] / 409)
// ---------------------------------------------------------------------------
__global__ void finalize_kernel(const double* __restrict__ totS,
                                const double* __restrict__ accA,
                                float* __restrict__ out) {
  const int b = threadIdx.x;
  if (b < B_SZ) {
    double acc = 0.0;
    for (int p = 0; p < 5; ++p)
      acc += totS[p] * (accA[p * 4 + b] / (double)SEED_NUM);
    out[b] = (float)(acc / 5.0);
  }
}

__global__ void zero_kernel(double* __restrict__ ptr) {
  const int t = threadIdx.x;
  if (t < 25) ptr[t] = 0.0;  // totS[5] + accA[20]
}

extern "C" void kernel_launch(void* const* d_in, const int* in_sizes, int n_in,
                              void* d_out, int out_size, void* d_ws,
                              size_t ws_size, hipStream_t stream) {
  (void)in_sizes; (void)n_in; (void)out_size; (void)ws_size;
  const float* pcs = (const float*)d_in[0];
  float* out = (float*)d_out;

  // ws layout: seeds (B*409*3 f32 = 19632 B, 8-aligned), then 25 doubles.
  float* seeds = (float*)d_ws;
  double* sums = (double*)((char*)d_ws + 19632);

  zero_kernel<<<1, 32, 0, stream>>>(sums);
  fps_kernel<<<B_SZ, FPS_THREADS, 0, stream>>>(pcs, seeds);
  group_kernel<<<B_SZ * SEED_NUM, 256, 0, stream>>>(pcs, seeds, sums, sums + 5);
  finalize_kernel<<<1, 64, 0, stream>>>(sums, sums + 5, out);
}

// Round 9
// 565.498 us; speedup vs baseline: 1.1036x; 1.0117x over previous
//
#include <hip/hip_runtime.h>
#include <math.h>

#define N_PTS 8192
#define B_SZ 4
#define SEED_NUM 409
#define FPS_THREADS 512
#define LTOT 653  // 65+98+131+163+196

typedef float f2 __attribute__((ext_vector_type(2)));

// Exact IEEE f32 squared distance, same op order as the reference:
// ((dx*dx + dy*dy) + dz*dz), no FMA contraction.
__device__ __forceinline__ float sqdist(float ax, float ay, float az,
                                        float bx, float by, float bz) {
  float dx = __fsub_rn(ax, bx);
  float dy = __fsub_rn(ay, by);
  float dz = __fsub_rn(az, bz);
  return __fadd_rn(__fadd_rn(__fmul_rn(dx, dx), __fmul_rn(dy, dy)),
                   __fmul_rn(dz, dz));
}

#define FOR8(M) M(0) M(1) M(2) M(3) M(4) M(5) M(6) M(7)

// u64 lane-move via two 32-bit DPP ops (ctrl fields must be constant
// expressions -> template params). shr-stages: bound_ctrl=1 (OOB lanes
// read 0 — harmless for max of non-negative keys). bcast stages keep `old`
// in masked-off rows so the subsequent max is a no-op there.
template <int CTRL>
__device__ __forceinline__ unsigned long long dpp_u64_bc1(
    unsigned long long k) {
  const unsigned lo2 = (unsigned)__builtin_amdgcn_update_dpp(
      0, (int)(unsigned)k, CTRL, 0xf, 0xf, true);
  const unsigned hi2 = (unsigned)__builtin_amdgcn_update_dpp(
      0, (int)(unsigned)(k >> 32), CTRL, 0xf, 0xf, true);
  return ((unsigned long long)hi2 << 32) | lo2;
}
template <int CTRL, int ROW_MASK>
__device__ __forceinline__ unsigned long long dpp_u64_keep(
    unsigned long long k) {
  const unsigned lo2 = (unsigned)__builtin_amdgcn_update_dpp(
      (int)(unsigned)k, (int)(unsigned)k, CTRL, ROW_MASK, 0xf, false);
  const unsigned hi2 = (unsigned)__builtin_amdgcn_update_dpp(
      (int)(unsigned)(k >> 32), (int)(unsigned)(k >> 32), CTRL, ROW_MASK, 0xf,
      false);
  return ((unsigned long long)hi2 << 32) | lo2;
}

// ---------------------------------------------------------------------------
// Kernel 1: farthest point sampling. One block per batch (4 blocks).
// R8 counters: VALU-busy ~72% on active CUs -> near issue-bound. R9 change:
// distance update in PACKED f32 (v_pk_add/v_pk_mul, full-rate on CDNA4) via
// float2 ext-vectors, fp contract OFF so each half is the exact scalar IEEE
// sequence (bitwise-identical results, half the distance instructions).
// Wave argmax: u64-key DPP reduce (R6). Coords pinned via asm (R4).
// Block 0 also zeroes the 25 accumulator doubles (replaces zero_kernel
// dispatch; stream order makes them visible to group_kernel).
// ---------------------------------------------------------------------------
__global__ __launch_bounds__(FPS_THREADS, 1) void fps_kernel(
    const float* __restrict__ pcs, float* __restrict__ seeds,
    double* __restrict__ sums /*25 doubles*/) {
#pragma clang fp contract(off)
  const int b = blockIdx.x;
  const int tid = threadIdx.x;
  const int lane = tid & 63, wid = tid >> 6;  // 8 waves
  const float* base = pcs + (size_t)b * N_PTS * 3;

  if (b == 0 && tid < 25) sums[tid] = 0.0;  // zero totS[5]+accA[20]

  __shared__ float spts[N_PTS * 3];        // 96 KiB: winner-coord broadcast
  __shared__ float seedbuf[SEED_NUM * 3];  // 4.8 KiB: deferred seed output
  __shared__ unsigned long long red[2][8];

  // pair j holds points i0 = tid + (2j)*512 and i1 = tid + (2j+1)*512
#define FPS_DECL(j) f2 px##j, py##j, pz##j, md##j;
  FOR8(FPS_DECL)
#undef FPS_DECL

#define FPS_INIT(j)                                   \
  {                                                   \
    const int i0 = tid + (2 * (j)) * FPS_THREADS;     \
    const int i1 = i0 + FPS_THREADS;                  \
    px##j = (f2){base[i0 * 3 + 0], base[i1 * 3 + 0]}; \
    py##j = (f2){base[i0 * 3 + 1], base[i1 * 3 + 1]}; \
    pz##j = (f2){base[i0 * 3 + 2], base[i1 * 3 + 2]}; \
    md##j = (f2){1e10f, 1e10f}; /* ref 1e10 exact */  \
    spts[i0 * 3 + 0] = px##j.x;                       \
    spts[i0 * 3 + 1] = py##j.x;                       \
    spts[i0 * 3 + 2] = pz##j.x;                       \
    spts[i1 * 3 + 0] = px##j.y;                       \
    spts[i1 * 3 + 1] = py##j.y;                       \
    spts[i1 * 3 + 2] = pz##j.y;                       \
  }
  FOR8(FPS_INIT)
#undef FPS_INIT

  // Pin coords in VGPRs (asm results can't be rematerialized from memory).
#define FPS_PIN(j) asm volatile("" : "+v"(px##j), "+v"(py##j), "+v"(pz##j));
  FOR8(FPS_PIN)
#undef FPS_PIN

  float cx = base[0], cy = base[1], cz = base[2];

  for (int s = 0; s < SEED_NUM; ++s) {
    if (tid == 0) {
      seedbuf[s * 3 + 0] = cx;
      seedbuf[s * 3 + 1] = cy;
      seedbuf[s * 3 + 2] = cz;
    }
    const f2 ccx = (f2){cx, cx}, ccy = (f2){cy, cy}, ccz = (f2){cz, cz};
    float bv = -1.0f;
    int bi = 0;
    // ascending index order + strict '>' keeps the first index on ties.
#define FPS_UPD(j)                                                  \
  {                                                                 \
    const f2 dx = px##j - ccx;                                      \
    const f2 dy = py##j - ccy;                                      \
    const f2 dz = pz##j - ccz;                                      \
    const f2 t0 = dx * dx;                                          \
    const f2 t1 = dy * dy;                                          \
    const f2 t2 = dz * dz;                                          \
    const f2 d2 = (t0 + t1) + t2;                                   \
    const f2 m = __builtin_elementwise_min(md##j, d2);              \
    md##j = m;                                                      \
    if (m.x > bv) { bv = m.x; bi = tid + (2 * (j)) * FPS_THREADS; } \
    if (m.y > bv) { bv = m.y; bi = tid + (2 * (j) + 1) * FPS_THREADS; } \
  }
    FOR8(FPS_UPD)
#undef FPS_UPD
    // packed argmax key: bv >= 0 so f32 bits are monotone; u64 max ==
    // (max value, tie -> min index) == jnp.argmax semantics.
    unsigned long long key =
        ((unsigned long long)__float_as_uint(bv) << 32) |
        (unsigned long long)(unsigned)(N_PTS - 1 - bi);
    unsigned long long o;
    o = dpp_u64_bc1<0x111>(key);         key = (o > key) ? o : key;  // shr 1
    o = dpp_u64_bc1<0x112>(key);         key = (o > key) ? o : key;  // shr 2
    o = dpp_u64_bc1<0x114>(key);         key = (o > key) ? o : key;  // shr 4
    o = dpp_u64_bc1<0x118>(key);         key = (o > key) ? o : key;  // shr 8
    o = dpp_u64_keep<0x142, 0xa>(key);   key = (o > key) ? o : key;  // bcast15
    o = dpp_u64_keep<0x143, 0xc>(key);   key = (o > key) ? o : key;  // bcast31
    if (lane == 63) red[s & 1][wid] = key;
    __syncthreads();
    unsigned long long kmax = red[s & 1][0];
#pragma unroll
    for (int w = 1; w < 8; ++w) {
      const unsigned long long t = red[s & 1][w];
      kmax = (t > kmax) ? t : kmax;
    }
    const int ci = N_PTS - 1 - (int)(unsigned)(kmax & 0xffffffffull);
    cx = spts[ci * 3 + 0];
    cy = spts[ci * 3 + 1];
    cz = spts[ci * 3 + 2];
  }

  // bulk seed writeback (ordered by the final in-loop barrier)
  __syncthreads();
  float* sg = seeds + (size_t)b * SEED_NUM * 3;
  for (int i = tid; i < SEED_NUM * 3; i += FPS_THREADS) sg[i] = seedbuf[i];
}

// ---------------------------------------------------------------------------
// Kernel 2: one block per group, ALL 5 percentages at once (unchanged —
// est. ~30-40 us). Order-free atomic-append collection (valid-sets nest, KNN
// is set-order-independent); ordered-recompaction fallback for the
// measure-zero cnt>K case; 4-thread/row two-min KNN with shfl_xor merge.
// ---------------------------------------------------------------------------
__global__ __launch_bounds__(256) void group_kernel(
    const float* __restrict__ pcs, const float* __restrict__ seeds,
    double* __restrict__ totS /*[5]*/, double* __restrict__ accA /*[5][4]*/) {
  const int g = blockIdx.x;  // 0 .. B*SEED_NUM-1
  const int b = g / SEED_NUM;
  const int tid = threadIdx.x;
  const int lane = tid & 63, wid = tid >> 6;

  const int Kc[5] = {65, 98, 131, 163, 196};
  const int off[5] = {0, 65, 163, 294, 457};
  const double Pd[5] = {0.004, 0.006, 0.008, 0.01, 0.012};
  float r2c[5], expnf[5], expdc[5];
#pragma unroll
  for (int p = 0; p < 5; ++p) {
    const double pd = Pd[p];
    const double rd = sqrt(pd);
    r2c[p] = (float)(rd * rd);                     // weak f32 cast of r*r
    const double expn_d = 8192.0 * pd;
    expnf[p] = (float)expn_d;
    expdc[p] = sqrtf((float)(M_PI / expn_d * pd));  // expect_dis (= sqrt(pi/N))
  }

  const float* base = pcs + (size_t)b * N_PTS * 3;
  const float* sp = seeds + (size_t)g * 3;
  const float sx = sp[0], sy = sp[1], sz = sp[2];

  __shared__ float lx[LTOT], ly[LTOT], lz[LTOT];
  __shared__ int cnt[5];
  __shared__ int wtot[4];     // fallback path only
  __shared__ double wsum[4];

  if (tid < 5) cnt[tid] = 0;
  __syncthreads();

  // ---- single barrier-free scan: d2 once, append to each nested list ----
  const float r2max = r2c[4];
  for (int i = tid; i < N_PTS; i += 256) {
    const float x = base[i * 3 + 0];
    const float y = base[i * 3 + 1];
    const float z = base[i * 3 + 2];
    const float d2 = sqdist(x, y, z, sx, sy, sz);
    if (d2 < r2max) {
#pragma unroll
      for (int p = 0; p < 5; ++p) {
        if (d2 < r2c[p]) {
          const int pos = atomicAdd(&cnt[p], 1);
          if (pos < Kc[p]) {
            lx[off[p] + pos] = x;
            ly[off[p] + pos] = y;
            lz[off[p] + pos] = z;
          }
        }
      }
    }
  }
  __syncthreads();

  // ---- rare fallback: cnt>K needs the K smallest indices (ordered) ----
#pragma unroll
  for (int p = 0; p < 5; ++p) {
    if (cnt[p] > Kc[p]) {  // block-uniform (LDS value, post-barrier)
      int run = 0;
      for (int base_i = 0; base_i < N_PTS; base_i += 256) {
        const int i = base_i + tid;
        const float x = base[i * 3 + 0];
        const float y = base[i * 3 + 1];
        const float z = base[i * 3 + 2];
        const float d2 = sqdist(x, y, z, sx, sy, sz);
        const bool valid = d2 < r2c[p];
        const unsigned long long m = __ballot(valid);
        if (lane == 0) wtot[wid] = __popcll(m);
        __syncthreads();
        int pos = run + __popcll(m & ((1ull << lane) - 1ull));
        for (int w = 0; w < wid; ++w) pos += wtot[w];
        if (valid && pos < Kc[p]) {
          lx[off[p] + pos] = x; ly[off[p] + pos] = y; lz[off[p] + pos] = z;
        }
        run += wtot[0] + wtot[1] + wtot[2] + wtot[3];
        __syncthreads();
      }
    }
  }

  // ---- KNN + clutter per percentage: 4 threads/row, shfl two-min merge ----
#pragma unroll
  for (int p = 0; p < 5; ++p) {
    const int gn = min(cnt[p], Kc[p]);  // gnum >= 1 (seed itself is in pcs)
    const float ed = expdc[p];
    const int lb = off[p];
    double localS = 0.0;
    for (int r0 = 0; r0 < gn; r0 += 64) {
      const int row = r0 + (tid >> 2);
      const int sub = tid & 3;
      float m1 = INFINITY, m2 = INFINITY;
      if (row < gn) {
        const float xi = lx[lb + row], yi = ly[lb + row], zi = lz[lb + row];
        for (int j = sub; j < gn; j += 4) {
          const float d2 = sqdist(xi, yi, zi, lx[lb + j], ly[lb + j], lz[lb + j]);
          if (d2 < m1) { m2 = m1; m1 = d2; }
          else if (d2 < m2) { m2 = d2; }
        }
      }
      // merge (m1,m2) pairs across the 4 sub-lanes (multiset two-min)
#pragma unroll
      for (int d = 1; d <= 2; d <<= 1) {
        const float om1 = __shfl_xor(m1, d);
        const float om2 = __shfl_xor(m2, d);
        const float lo = fminf(m1, om1);
        const float hi = fmaxf(m1, om1);
        m2 = fminf(fminf(m2, om2), hi);
        m1 = lo;
      }
      if (row < gn && sub == 0) {
        const float nn2 = (m2 > 1e37f) ? 0.0f : m2;  // inf (gn==1) -> 0
        const float nnd = (nn2 > 0.0f) ? sqrtf(nn2) : 0.0f;
        const float diff = __fsub_rn(nnd, ed);
        const float clut = __fdiv_rn(__fmul_rn(diff, diff),
                                     __fadd_rn(ed, 1e-12f));
        localS += (double)clut;
      }
    }
#pragma unroll
    for (int o = 32; o > 0; o >>= 1) localS += __shfl_down(localS, o);
    if (lane == 0) wsum[wid] = localS;
    __syncthreads();
    if (tid == 0) {
      const double S = wsum[0] + wsum[1] + wsum[2] + wsum[3];
      atomicAdd(&totS[p], S);
      const float gf = (float)gn;
      const float dd = __fsub_rn(gf, expnf[p]);
      const float imb = __fdiv_rn(__fmul_rn(dd, dd), expnf[p]);
      atomicAdd(&accA[p * 4 + b], (double)imb / (double)gf);
    }
    __syncthreads();  // wsum reused next p
  }
}

// ---------------------------------------------------------------------------
// Kernel 3: loss[b] = (1/5) * sum_p totS[p] * (accA[p][b] / 409)
// ---------------------------------------------------------------------------
__global__ void finalize_kernel(const double* __restrict__ totS,
                                const double* __restrict__ accA,
                                float* __restrict__ out) {
  const int b = threadIdx.x;
  if (b < B_SZ) {
    double acc = 0.0;
    for (int p = 0; p < 5; ++p)
      acc += totS[p] * (accA[p * 4 + b] / (double)SEED_NUM);
    out[b] = (float)(acc / 5.0);
  }
}

extern "C" void kernel_launch(void* const* d_in, const int* in_sizes, int n_in,
                              void* d_out, int out_size, void* d_ws,
                              size_t ws_size, hipStream_t stream) {
  (void)in_sizes; (void)n_in; (void)out_size; (void)ws_size;
  const float* pcs = (const float*)d_in[0];
  float* out = (float*)d_out;

  // ws layout: seeds (B*409*3 f32 = 19632 B, 8-aligned), then 25 doubles.
  float* seeds = (float*)d_ws;
  double* sums = (double*)((char*)d_ws + 19632);

  fps_kernel<<<B_SZ, FPS_THREADS, 0, stream>>>(pcs, seeds, sums);
  group_kernel<<<B_SZ * SEED_NUM, 256, 0, stream>>>(pcs, seeds, sums, sums + 5);
  finalize_kernel<<<1, 64, 0, stream>>>(sums, sums + 5, out);
}

// Round 10
// 482.052 us; speedup vs baseline: 1.2946x; 1.1731x over previous
//
#include <hip/hip_runtime.h>
#include <math.h>

#define N_PTS 8192
#define B_SZ 4
#define SEED_NUM 409
#define FPS_THREADS 256  // 4 waves, 1 per SIMD
#define LTOT 653  // 65+98+131+163+196

typedef float f2 __attribute__((ext_vector_type(2)));
typedef float f4 __attribute__((ext_vector_type(4)));

// Exact IEEE f32 squared distance, same op order as the reference:
// ((dx*dx + dy*dy) + dz*dz), no FMA contraction.
__device__ __forceinline__ float sqdist(float ax, float ay, float az,
                                        float bx, float by, float bz) {
  float dx = __fsub_rn(ax, bx);
  float dy = __fsub_rn(ay, by);
  float dz = __fsub_rn(az, bz);
  return __fadd_rn(__fadd_rn(__fmul_rn(dx, dx), __fmul_rn(dy, dy)),
                   __fmul_rn(dz, dz));
}

#define FOR16(M) \
  M(0) M(1) M(2) M(3) M(4) M(5) M(6) M(7) \
  M(8) M(9) M(10) M(11) M(12) M(13) M(14) M(15)

// u64 lane-move via two 32-bit DPP ops (ctrl fields must be constant
// expressions -> template params). shr-stages: bound_ctrl=1 (OOB lanes
// read 0 — harmless for max of non-negative keys). bcast stages keep `old`
// in masked-off rows so the subsequent max is a no-op there.
template <int CTRL>
__device__ __forceinline__ unsigned long long dpp_u64_bc1(
    unsigned long long k) {
  const unsigned lo2 = (unsigned)__builtin_amdgcn_update_dpp(
      0, (int)(unsigned)k, CTRL, 0xf, 0xf, true);
  const unsigned hi2 = (unsigned)__builtin_amdgcn_update_dpp(
      0, (int)(unsigned)(k >> 32), CTRL, 0xf, 0xf, true);
  return ((unsigned long long)hi2 << 32) | lo2;
}
template <int CTRL, int ROW_MASK>
__device__ __forceinline__ unsigned long long dpp_u64_keep(
    unsigned long long k) {
  const unsigned lo2 = (unsigned)__builtin_amdgcn_update_dpp(
      (int)(unsigned)k, (int)(unsigned)k, CTRL, ROW_MASK, 0xf, false);
  const unsigned hi2 = (unsigned)__builtin_amdgcn_update_dpp(
      (int)(unsigned)(k >> 32), (int)(unsigned)(k >> 32), CTRL, ROW_MASK, 0xf,
      false);
  return ((unsigned long long)hi2 << 32) | lo2;
}

// ---------------------------------------------------------------------------
// Kernel 1: farthest point sampling. One block per batch (4 blocks).
// R9 evidence: halving VALU instrs (packed math) was ~neutral -> step is
// wave-count-bound (barrier spread, per-SIMD dual-wave serialization, scan
// length), matching R1->R2 (16->8 waves = 2.44x). R10 change: 4 waves
// (256 thr, 1 wave/SIMD), 32 pts/thread in f2 pairs (~180 VGPR, no spill
// below 450); 4-partial scan; spts stored as float4 so the winner broadcast
// is one ds_read_b128.
// (R8: packed f32 + fused accumulator zeroing. R6: DPP argmax reduce.
//  R4: asm "+v" pin keeps coords in VGPRs.)
// ---------------------------------------------------------------------------
__global__ __launch_bounds__(FPS_THREADS, 1) void fps_kernel(
    const float* __restrict__ pcs, float* __restrict__ seeds,
    double* __restrict__ sums /*25 doubles*/) {
#pragma clang fp contract(off)
  const int b = blockIdx.x;
  const int tid = threadIdx.x;
  const int lane = tid & 63, wid = tid >> 6;  // 4 waves
  const float* base = pcs + (size_t)b * N_PTS * 3;

  if (b == 0 && tid < 25) sums[tid] = 0.0;  // zero totS[5]+accA[20]

  __shared__ f4 spts4[N_PTS];              // 128 KiB: winner-coord broadcast
  __shared__ float seedbuf[SEED_NUM * 3];  // 4.8 KiB: deferred seed output
  __shared__ unsigned long long red[2][4];

  // pair j holds points i0 = tid + (2j)*256 and i1 = tid + (2j+1)*256
#define FPS_DECL(j) f2 px##j, py##j, pz##j, md##j;
  FOR16(FPS_DECL)
#undef FPS_DECL

#define FPS_INIT(j)                                   \
  {                                                   \
    const int i0 = tid + (2 * (j)) * FPS_THREADS;     \
    const int i1 = i0 + FPS_THREADS;                  \
    px##j = (f2){base[i0 * 3 + 0], base[i1 * 3 + 0]}; \
    py##j = (f2){base[i0 * 3 + 1], base[i1 * 3 + 1]}; \
    pz##j = (f2){base[i0 * 3 + 2], base[i1 * 3 + 2]}; \
    md##j = (f2){1e10f, 1e10f}; /* ref 1e10 exact */  \
    spts4[i0] = (f4){px##j.x, py##j.x, pz##j.x, 0.f}; \
    spts4[i1] = (f4){px##j.y, py##j.y, pz##j.y, 0.f}; \
  }
  FOR16(FPS_INIT)
#undef FPS_INIT

  // Pin coords in VGPRs (asm results can't be rematerialized from memory).
#define FPS_PIN(j) asm volatile("" : "+v"(px##j), "+v"(py##j), "+v"(pz##j));
  FOR16(FPS_PIN)
#undef FPS_PIN

  float cx = base[0], cy = base[1], cz = base[2];

  for (int s = 0; s < SEED_NUM; ++s) {
    if (tid == 0) {
      seedbuf[s * 3 + 0] = cx;
      seedbuf[s * 3 + 1] = cy;
      seedbuf[s * 3 + 2] = cz;
    }
    const f2 ccx = (f2){cx, cx}, ccy = (f2){cy, cy}, ccz = (f2){cz, cz};
    float bv = -1.0f;
    int bi = 0;
    // ascending index order + strict '>' keeps the first index on ties.
#define FPS_UPD(j)                                                      \
  {                                                                     \
    const f2 dx = px##j - ccx;                                          \
    const f2 dy = py##j - ccy;                                          \
    const f2 dz = pz##j - ccz;                                          \
    const f2 t0 = dx * dx;                                              \
    const f2 t1 = dy * dy;                                              \
    const f2 t2 = dz * dz;                                              \
    const f2 d2 = (t0 + t1) + t2;                                       \
    const f2 m = __builtin_elementwise_min(md##j, d2);                  \
    md##j = m;                                                          \
    if (m.x > bv) { bv = m.x; bi = tid + (2 * (j)) * FPS_THREADS; }     \
    if (m.y > bv) { bv = m.y; bi = tid + (2 * (j) + 1) * FPS_THREADS; } \
  }
    FOR16(FPS_UPD)
#undef FPS_UPD
    // packed argmax key: bv >= 0 so f32 bits are monotone; u64 max ==
    // (max value, tie -> min index) == jnp.argmax semantics.
    unsigned long long key =
        ((unsigned long long)__float_as_uint(bv) << 32) |
        (unsigned long long)(unsigned)(N_PTS - 1 - bi);
    unsigned long long o;
    o = dpp_u64_bc1<0x111>(key);         key = (o > key) ? o : key;  // shr 1
    o = dpp_u64_bc1<0x112>(key);         key = (o > key) ? o : key;  // shr 2
    o = dpp_u64_bc1<0x114>(key);         key = (o > key) ? o : key;  // shr 4
    o = dpp_u64_bc1<0x118>(key);         key = (o > key) ? o : key;  // shr 8
    o = dpp_u64_keep<0x142, 0xa>(key);   key = (o > key) ? o : key;  // bcast15
    o = dpp_u64_keep<0x143, 0xc>(key);   key = (o > key) ? o : key;  // bcast31
    if (lane == 63) red[s & 1][wid] = key;
    __syncthreads();
    unsigned long long kmax = red[s & 1][0];
#pragma unroll
    for (int w = 1; w < 4; ++w) {
      const unsigned long long t = red[s & 1][w];
      kmax = (t > kmax) ? t : kmax;
    }
    const int ci = N_PTS - 1 - (int)(unsigned)(kmax & 0xffffffffull);
    const f4 c = spts4[ci];  // one ds_read_b128, same-address broadcast
    cx = c.x;
    cy = c.y;
    cz = c.z;
  }

  // bulk seed writeback (ordered by the final in-loop barrier)
  __syncthreads();
  float* sg = seeds + (size_t)b * SEED_NUM * 3;
  for (int i = tid; i < SEED_NUM * 3; i += FPS_THREADS) sg[i] = seedbuf[i];
}

// ---------------------------------------------------------------------------
// Kernel 2: one block per group, ALL 5 percentages at once (unchanged —
// est. ~30-40 us). Order-free atomic-append collection (valid-sets nest, KNN
// is set-order-independent); ordered-recompaction fallback for the
// measure-zero cnt>K case; 4-thread/row two-min KNN with shfl_xor merge.
// ---------------------------------------------------------------------------
__global__ __launch_bounds__(256) void group_kernel(
    const float* __restrict__ pcs, const float* __restrict__ seeds,
    double* __restrict__ totS /*[5]*/, double* __restrict__ accA /*[5][4]*/) {
  const int g = blockIdx.x;  // 0 .. B*SEED_NUM-1
  const int b = g / SEED_NUM;
  const int tid = threadIdx.x;
  const int lane = tid & 63, wid = tid >> 6;

  const int Kc[5] = {65, 98, 131, 163, 196};
  const int off[5] = {0, 65, 163, 294, 457};
  const double Pd[5] = {0.004, 0.006, 0.008, 0.01, 0.012};
  float r2c[5], expnf[5], expdc[5];
#pragma unroll
  for (int p = 0; p < 5; ++p) {
    const double pd = Pd[p];
    const double rd = sqrt(pd);
    r2c[p] = (float)(rd * rd);                     // weak f32 cast of r*r
    const double expn_d = 8192.0 * pd;
    expnf[p] = (float)expn_d;
    expdc[p] = sqrtf((float)(M_PI / expn_d * pd));  // expect_dis (= sqrt(pi/N))
  }

  const float* base = pcs + (size_t)b * N_PTS * 3;
  const float* sp = seeds + (size_t)g * 3;
  const float sx = sp[0], sy = sp[1], sz = sp[2];

  __shared__ float lx[LTOT], ly[LTOT], lz[LTOT];
  __shared__ int cnt[5];
  __shared__ int wtot[4];     // fallback path only
  __shared__ double wsum[4];

  if (tid < 5) cnt[tid] = 0;
  __syncthreads();

  // ---- single barrier-free scan: d2 once, append to each nested list ----
  const float r2max = r2c[4];
  for (int i = tid; i < N_PTS; i += 256) {
    const float x = base[i * 3 + 0];
    const float y = base[i * 3 + 1];
    const float z = base[i * 3 + 2];
    const float d2 = sqdist(x, y, z, sx, sy, sz);
    if (d2 < r2max) {
#pragma unroll
      for (int p = 0; p < 5; ++p) {
        if (d2 < r2c[p]) {
          const int pos = atomicAdd(&cnt[p], 1);
          if (pos < Kc[p]) {
            lx[off[p] + pos] = x;
            ly[off[p] + pos] = y;
            lz[off[p] + pos] = z;
          }
        }
      }
    }
  }
  __syncthreads();

  // ---- rare fallback: cnt>K needs the K smallest indices (ordered) ----
#pragma unroll
  for (int p = 0; p < 5; ++p) {
    if (cnt[p] > Kc[p]) {  // block-uniform (LDS value, post-barrier)
      int run = 0;
      for (int base_i = 0; base_i < N_PTS; base_i += 256) {
        const int i = base_i + tid;
        const float x = base[i * 3 + 0];
        const float y = base[i * 3 + 1];
        const float z = base[i * 3 + 2];
        const float d2 = sqdist(x, y, z, sx, sy, sz);
        const bool valid = d2 < r2c[p];
        const unsigned long long m = __ballot(valid);
        if (lane == 0) wtot[wid] = __popcll(m);
        __syncthreads();
        int pos = run + __popcll(m & ((1ull << lane) - 1ull));
        for (int w = 0; w < wid; ++w) pos += wtot[w];
        if (valid && pos < Kc[p]) {
          lx[off[p] + pos] = x; ly[off[p] + pos] = y; lz[off[p] + pos] = z;
        }
        run += wtot[0] + wtot[1] + wtot[2] + wtot[3];
        __syncthreads();
      }
    }
  }

  // ---- KNN + clutter per percentage: 4 threads/row, shfl two-min merge ----
#pragma unroll
  for (int p = 0; p < 5; ++p) {
    const int gn = min(cnt[p], Kc[p]);  // gnum >= 1 (seed itself is in pcs)
    const float ed = expdc[p];
    const int lb = off[p];
    double localS = 0.0;
    for (int r0 = 0; r0 < gn; r0 += 64) {
      const int row = r0 + (tid >> 2);
      const int sub = tid & 3;
      float m1 = INFINITY, m2 = INFINITY;
      if (row < gn) {
        const float xi = lx[lb + row], yi = ly[lb + row], zi = lz[lb + row];
        for (int j = sub; j < gn; j += 4) {
          const float d2 = sqdist(xi, yi, zi, lx[lb + j], ly[lb + j], lz[lb + j]);
          if (d2 < m1) { m2 = m1; m1 = d2; }
          else if (d2 < m2) { m2 = d2; }
        }
      }
      // merge (m1,m2) pairs across the 4 sub-lanes (multiset two-min)
#pragma unroll
      for (int d = 1; d <= 2; d <<= 1) {
        const float om1 = __shfl_xor(m1, d);
        const float om2 = __shfl_xor(m2, d);
        const float lo = fminf(m1, om1);
        const float hi = fmaxf(m1, om1);
        m2 = fminf(fminf(m2, om2), hi);
        m1 = lo;
      }
      if (row < gn && sub == 0) {
        const float nn2 = (m2 > 1e37f) ? 0.0f : m2;  // inf (gn==1) -> 0
        const float nnd = (nn2 > 0.0f) ? sqrtf(nn2) : 0.0f;
        const float diff = __fsub_rn(nnd, ed);
        const float clut = __fdiv_rn(__fmul_rn(diff, diff),
                                     __fadd_rn(ed, 1e-12f));
        localS += (double)clut;
      }
    }
#pragma unroll
    for (int o = 32; o > 0; o >>= 1) localS += __shfl_down(localS, o);
    if (lane == 0) wsum[wid] = localS;
    __syncthreads();
    if (tid == 0) {
      const double S = wsum[0] + wsum[1] + wsum[2] + wsum[3];
      atomicAdd(&totS[p], S);
      const float gf = (float)gn;
      const float dd = __fsub_rn(gf, expnf[p]);
      const float imb = __fdiv_rn(__fmul_rn(dd, dd), expnf[p]);
      atomicAdd(&accA[p * 4 + b], (double)imb / (double)gf);
    }
    __syncthreads();  // wsum reused next p
  }
}

// ---------------------------------------------------------------------------
// Kernel 3: loss[b] = (1/5) * sum_p totS[p] * (accA[p][b] / 409)
// ---------------------------------------------------------------------------
__global__ void finalize_kernel(const double* __restrict__ totS,
                                const double* __restrict__ accA,
                                float* __restrict__ out) {
  const int b = threadIdx.x;
  if (b < B_SZ) {
    double acc = 0.0;
    for (int p = 0; p < 5; ++p)
      acc += totS[p] * (accA[p * 4 + b] / (double)SEED_NUM);
    out[b] = (float)(acc / 5.0);
  }
}

extern "C" void kernel_launch(void* const* d_in, const int* in_sizes, int n_in,
                              void* d_out, int out_size, void* d_ws,
                              size_t ws_size, hipStream_t stream) {
  (void)in_sizes; (void)n_in; (void)out_size; (void)ws_size;
  const float* pcs = (const float*)d_in[0];
  float* out = (float*)d_out;

  // ws layout: seeds (B*409*3 f32 = 19632 B, 8-aligned), then 25 doubles.
  float* seeds = (float*)d_ws;
  double* sums = (double*)((char*)d_ws + 19632);

  fps_kernel<<<B_SZ, FPS_THREADS, 0, stream>>>(pcs, seeds, sums);
  group_kernel<<<B_SZ * SEED_NUM, 256, 0, stream>>>(pcs, seeds, sums, sums + 5);
  finalize_kernel<<<1, 64, 0, stream>>>(sums, sums + 5, out);
}